// Round 4
// baseline (441.438 us; speedup 1.0000x reference)
//
#include <hip/hip_runtime.h>

#define BB 4
#define TT 32
#define DD 256
#define NN 1024

// ws layout (float indices)
#define XN_OFF 0                      // xn_buf [B*T][N]
#define TN_OFF (BB*TT*NN)             // tn_buf [B*T][N]  (tn_buf[b][t] = tgt_neurons[b][t+1])
#define PB_OFF (2*BB*TT*NN)           // pb64  [(b*T+t)*2 + phase][N] of u64 (value<<32 | seq)
#define YW_OFF (PB_OFF + 4*BB*TT*NN)  // y_ws  [B*T][D]

// ------------- kernel 1: xn = relu(LN(x @ E)), tn shifted; 4 rows/block -------------
// Grid must be BB*TT/2 = 64 blocks (each handles 2 bt's x {x_seq, targets}).
__global__ __launch_bounds__(256) void precompute_kernel(
    const float* __restrict__ x_seq, const float* __restrict__ targets,
    const float* __restrict__ E, float* __restrict__ ws)
{
    __shared__ float xr[4][DD];
    __shared__ float redS[4][4], redSS[4][4];
    const int blk = blockIdx.x;        // 0..63
    const int bt0 = blk * 2;
    const int bt1 = bt0 + 1;
    const int tid = threadIdx.x;       // 0..255
    const int lane = tid & 63, w = tid >> 6;

    xr[0][tid] = x_seq[(size_t)bt0 * DD + tid];
    xr[1][tid] = x_seq[(size_t)bt1 * DD + tid];
    xr[2][tid] = targets[(size_t)bt0 * DD + tid];
    xr[3][tid] = targets[(size_t)bt1 * DD + tid];
    __syncthreads();

    const float4* E4 = (const float4*)E;
    float4 acc[4];
#pragma unroll
    for (int r = 0; r < 4; ++r) acc[r] = make_float4(0.f, 0.f, 0.f, 0.f);
#pragma unroll 4
    for (int k = 0; k < DD; ++k) {
        float4 e = E4[(size_t)k * (NN / 4) + tid];
#pragma unroll
        for (int r = 0; r < 4; ++r) {
            float xv = xr[r][k];
            acc[r].x += xv * e.x; acc[r].y += xv * e.y;
            acc[r].z += xv * e.z; acc[r].w += xv * e.w;
        }
    }
    float s[4], ss[4];
#pragma unroll
    for (int r = 0; r < 4; ++r) {
        s[r]  = acc[r].x + acc[r].y + acc[r].z + acc[r].w;
        ss[r] = acc[r].x*acc[r].x + acc[r].y*acc[r].y + acc[r].z*acc[r].z + acc[r].w*acc[r].w;
    }
#pragma unroll
    for (int d = 1; d < 64; d <<= 1) {
#pragma unroll
        for (int r = 0; r < 4; ++r) {
            s[r]  += __shfl_xor(s[r], d, 64);
            ss[r] += __shfl_xor(ss[r], d, 64);
        }
    }
    if (lane == 0) {
#pragma unroll
        for (int r = 0; r < 4; ++r) { redS[w][r] = s[r]; redSS[w][r] = ss[r]; }
    }
    __syncthreads();
#pragma unroll
    for (int r = 0; r < 4; ++r) {
        s[r]  = redS[0][r] + redS[1][r] + redS[2][r] + redS[3][r];
        ss[r] = redSS[0][r] + redSS[1][r] + redSS[2][r] + redSS[3][r];
    }

#pragma unroll
    for (int r = 0; r < 4; ++r) {
        const float mu  = s[r] * (1.0f / NN);
        const float var = ss[r] * (1.0f / NN) - mu * mu;
        const float inv = rsqrtf(var + 1e-5f);
        float4 o;
        o.x = fmaxf(0.f, (acc[r].x - mu) * inv);
        o.y = fmaxf(0.f, (acc[r].y - mu) * inv);
        o.z = fmaxf(0.f, (acc[r].z - mu) * inv);
        o.w = fmaxf(0.f, (acc[r].w - mu) * inv);
        const int bt = (r & 1) ? bt1 : bt0;
        float* dst = nullptr;
        if (r < 2) dst = ws + XN_OFF + (size_t)bt * NN;             // xn[bt]
        else if ((bt & 31) > 0) dst = ws + TN_OFF + (size_t)(bt - 1) * NN; // tn_next[bt-1]
        if (dst) ((float4*)dst)[tid] = o;
    }
}

// ------------- kernel 2: 3-stage spatial pipeline over the p1->p2->p3 chain -------------
// Stage s owns 64 cols per WG; each stage keeps its OWN G replica (updates depend only
// on precomputed xn/tn, never on the p-chain) so no stage ever waits on G.
// Stage 0: p1_t free-running. Stage 1: poll p1_t -> p2_t. Stage 2: poll p2_t -> p3, y.
// 192 blocks <= 256 CUs -> all co-resident; steady-state polls succeed first try.

__device__ __forceinline__ unsigned long long ld_slot(const unsigned long long* p) {
    return __hip_atomic_load(p, __ATOMIC_RELAXED, __HIP_MEMORY_SCOPE_AGENT);
}
__device__ __forceinline__ void st_slot(unsigned long long* p, unsigned long long v) {
    __hip_atomic_store(p, v, __ATOMIC_RELAXED, __HIP_MEMORY_SCOPE_AGENT);
}
__device__ __forceinline__ float poll_one(const unsigned long long* p, unsigned sq) {
    unsigned long long u; int g = 0;
    do {
        u = ld_slot(p);
    } while ((unsigned)u != sq && ++g < (1 << 24));
    return __uint_as_float((unsigned)(u >> 32));
}

__global__ __launch_bounds__(512, 2) void chain_pipeline(
    const float* __restrict__ Dy, float* __restrict__ ws)
{
    __shared__ float r_lds[64];
    const int blk   = blockIdx.x;      // 0..191
    const int stage = blk >> 6;        // 0,1,2 (stage 0 dispatched first)
    const int b     = (blk >> 4) & 3;
    const int wg    = blk & 15;
    const int tid   = threadIdx.x;
    const int lane  = tid & 63;
    const int w     = tid >> 6;        // wave 0..7
    const int colbase = wg * 64 + w * 8;   // wave owns cols colbase..colbase+7
    const int row0  = lane * 16;           // lane owns rows row0..row0+15

    const float* xn = ws + XN_OFF + (size_t)b * TT * NN;
    const float* tn = ws + TN_OFF + (size_t)b * TT * NN;
    unsigned long long* pb64 = (unsigned long long*)(ws + PB_OFF);
    float* yw = ws + YW_OFF;

    // G replica: 16 rows x 8 cols per lane, in VGPRs
    float G[16][8];
#pragma unroll
    for (int i = 0; i < 16; ++i)
#pragma unroll
        for (int c = 0; c < 8; ++c)
            G[i][c] = (row0 + i == colbase + c) ? 0.01f : 0.0f;

#pragma unroll 1
    for (int t = 0; t < TT; ++t) {
        const int bt = b * TT + t;
        unsigned long long* s1 = pb64 + (size_t)(bt * 2 + 0) * NN;
        unsigned long long* s2 = pb64 + (size_t)(bt * 2 + 1) * NN;
        const unsigned seq1 = (unsigned)(bt * 2 + 1);
        const unsigned seq2 = (unsigned)(bt * 2 + 2);

        float x[16];
        float acc[8] = {0.f,0.f,0.f,0.f,0.f,0.f,0.f,0.f};

        if (stage == 0) {
            // load xn_t rows straight into regs (coalesced: wave covers 4KB contiguous)
            const float4* xp = (const float4*)(xn + (size_t)t * NN + row0);
            float4 q0 = xp[0], q1 = xp[1], q2 = xp[2], q3 = xp[3];
            x[0]=q0.x; x[1]=q0.y; x[2]=q0.z; x[3]=q0.w;
            x[4]=q1.x; x[5]=q1.y; x[6]=q1.z; x[7]=q1.w;
            x[8]=q2.x; x[9]=q2.y; x[10]=q2.z; x[11]=q2.w;
            x[12]=q3.x; x[13]=q3.y; x[14]=q3.z; x[15]=q3.w;
#pragma unroll
            for (int i = 0; i < 16; ++i)
#pragma unroll
                for (int c = 0; c < 8; ++c) acc[c] += x[i] * G[i][c];
#pragma unroll
            for (int d = 1; d < 64; d <<= 1)
#pragma unroll
                for (int c = 0; c < 8; ++c) acc[c] += __shfl_xor(acc[c], d, 64);
            float vv = acc[0];
#pragma unroll
            for (int c = 1; c < 8; ++c) if ((lane & 7) == c) vv = acc[c];
            if (lane < 8) {
                unsigned long long u = ((unsigned long long)__float_as_uint(vv) << 32) | seq1;
                st_slot(s1 + colbase + lane, u);
            }
        } else {
            // poll the full input vector (16 contiguous u64 slots per lane)
            const unsigned long long* src = ((stage == 1) ? s1 : s2) + row0;
            const unsigned sq = (stage == 1) ? seq1 : seq2;
            unsigned long long vbuf[16];
            int guard = 0; bool ok;
            do {
                ok = true;
#pragma unroll
                for (int j = 0; j < 16; ++j) vbuf[j] = ld_slot(src + j);
#pragma unroll
                for (int j = 0; j < 16; ++j) ok &= ((unsigned)vbuf[j] == sq);
            } while (!ok && ++guard < (1 << 24));
            float p[16];
#pragma unroll
            for (int j = 0; j < 16; ++j) p[j] = __uint_as_float((unsigned)(vbuf[j] >> 32));

#pragma unroll
            for (int i = 0; i < 16; ++i)
#pragma unroll
                for (int c = 0; c < 8; ++c) acc[c] += p[i] * G[i][c];
#pragma unroll
            for (int d = 1; d < 64; d <<= 1)
#pragma unroll
                for (int c = 0; c < 8; ++c) acc[c] += __shfl_xor(acc[c], d, 64);
            float vv = acc[0];
#pragma unroll
            for (int c = 1; c < 8; ++c) if ((lane & 7) == c) vv = acc[c];

            if (stage == 1) {
                if (lane < 8) {
                    unsigned long long u = ((unsigned long long)__float_as_uint(vv) << 32) | seq2;
                    st_slot(s2 + colbase + lane, u);
                }
            } else {
                // reasoning r = max(p1,p2,p3) at own col, then y partial
                float v1own = poll_one(s1 + colbase + (lane & 7), seq1);
                float v2own = poll_one(s2 + colbase + (lane & 7), seq2);
                float r = fmaxf(vv, fmaxf(v1own, v2own));
                if (lane < 8) r_lds[w * 8 + lane] = r;
                __syncthreads();
                {
                    const int d = tid & 255;
                    const int h = tid >> 8;
                    float a = 0.f;
#pragma unroll
                    for (int j = 0; j < 32; ++j) {
                        const int cl = h * 32 + j;
                        a += r_lds[cl] * Dy[(size_t)(wg * 64 + cl) * DD + d];
                    }
                    atomicAdd(&yw[(size_t)bt * DD + d], a);
                }
                __syncthreads();  // r_lds reused next iteration
            }

            // stages 1,2 need xn_t only for the G update
            if (t < TT - 1) {
                const float4* xp = (const float4*)(xn + (size_t)t * NN + row0);
                float4 q0 = xp[0], q1 = xp[1], q2 = xp[2], q3 = xp[3];
                x[0]=q0.x; x[1]=q0.y; x[2]=q0.z; x[3]=q0.w;
                x[4]=q1.x; x[5]=q1.y; x[6]=q1.z; x[7]=q1.w;
                x[8]=q2.x; x[9]=q2.y; x[10]=q2.z; x[11]=q2.w;
                x[12]=q3.x; x[13]=q3.y; x[14]=q3.z; x[15]=q3.w;
            }
        }

        // ---- G update: G = max(G, 0.5*xn_t*tn_t^T), skip last step ----
        if (t < TT - 1) {
            float tnv = tn[(size_t)t * NN + colbase + (lane & 7)];
#pragma unroll
            for (int c = 0; c < 8; ++c) {
                const float tc = 0.5f * __shfl(tnv, c, 64);
#pragma unroll
                for (int i = 0; i < 16; ++i)
                    G[i][c] = fmaxf(G[i][c], x[i] * tc);
            }
        }
    }
}

// ------------- kernel 3: final relu -------------
__global__ __launch_bounds__(256) void relu_out_kernel(
    const float* __restrict__ yw, float* __restrict__ out, int n)
{
    int i = blockIdx.x * blockDim.x + threadIdx.x;
    if (i < n) out[i] = fmaxf(yw[i], 0.0f);
}

extern "C" void kernel_launch(void* const* d_in, const int* in_sizes, int n_in,
                              void* d_out, int out_size, void* d_ws, size_t ws_size,
                              hipStream_t stream) {
    const float* x_seq   = (const float*)d_in[0];
    const float* targets = (const float*)d_in[1];
    const float* E       = (const float*)d_in[2];
    const float* Dy      = (const float*)d_in[3];
    float* out = (float*)d_out;
    float* ws  = (float*)d_ws;

    // zero pb64 (flag slots; stale/poison != seq) + y accumulator (contiguous)
    hipMemsetAsync(ws + PB_OFF, 0,
                   (size_t)(4 * BB * TT * NN + BB * TT * DD) * sizeof(float), stream);

    precompute_kernel<<<BB * TT / 2, 256, 0, stream>>>(x_seq, targets, E, ws);
    chain_pipeline<<<3 * BB * 16, 512, 0, stream>>>(Dy, ws);
    relu_out_kernel<<<(BB * TT * DD + 255) / 256, 256, 0, stream>>>(ws + YW_OFF, out, BB * TT * DD);
}

// Round 5
// 267.121 us; speedup vs baseline: 1.6526x; 1.6526x over previous
//
#include <hip/hip_runtime.h>

#define BB 4
#define TT 32
#define DD 256
#define NN 1024

// ws layout (float indices)
#define XN_OFF   0                      // xn [B*T][N]
#define TN_OFF   131072                 // tn [B*T][N]  (tn[b][t] = tgt_neurons[b][t+1])
#define PB_OFF   262144                 // p  [B*T][2][N]
#define RB_OFF   524288                 // r  [B*T][N]
#define CNT_OFF  655360                 // cnt  [B*T*2][32] u32 (padded to 128B lines)
#define RCNT_OFF 663552                 // rcnt [B*T][32]  u32
#define WS_END   667648

// ---------------- kernel 1: xn = relu(LN(x @ E)), tn shifted; grid = 64 ----------------
__global__ __launch_bounds__(256) void precompute_kernel(
    const float* __restrict__ x_seq, const float* __restrict__ targets,
    const float* __restrict__ E, float* __restrict__ ws)
{
    __shared__ float xr[4][DD];
    __shared__ float redS[4][4], redSS[4][4];
    const int blk = blockIdx.x;        // 0..63
    const int bt0 = blk * 2, bt1 = bt0 + 1;
    const int tid = threadIdx.x;
    const int lane = tid & 63, w = tid >> 6;

    xr[0][tid] = x_seq[(size_t)bt0 * DD + tid];
    xr[1][tid] = x_seq[(size_t)bt1 * DD + tid];
    xr[2][tid] = targets[(size_t)bt0 * DD + tid];
    xr[3][tid] = targets[(size_t)bt1 * DD + tid];
    __syncthreads();

    const float4* E4 = (const float4*)E;
    float4 acc[4];
#pragma unroll
    for (int r = 0; r < 4; ++r) acc[r] = make_float4(0.f, 0.f, 0.f, 0.f);
#pragma unroll 4
    for (int k = 0; k < DD; ++k) {
        float4 e = E4[(size_t)k * (NN / 4) + tid];
#pragma unroll
        for (int r = 0; r < 4; ++r) {
            float xv = xr[r][k];
            acc[r].x += xv * e.x; acc[r].y += xv * e.y;
            acc[r].z += xv * e.z; acc[r].w += xv * e.w;
        }
    }
    float s[4], ss[4];
#pragma unroll
    for (int r = 0; r < 4; ++r) {
        s[r]  = acc[r].x + acc[r].y + acc[r].z + acc[r].w;
        ss[r] = acc[r].x*acc[r].x + acc[r].y*acc[r].y + acc[r].z*acc[r].z + acc[r].w*acc[r].w;
    }
#pragma unroll
    for (int d = 1; d < 64; d <<= 1) {
#pragma unroll
        for (int r = 0; r < 4; ++r) {
            s[r]  += __shfl_xor(s[r], d, 64);
            ss[r] += __shfl_xor(ss[r], d, 64);
        }
    }
    if (lane == 0) {
#pragma unroll
        for (int r = 0; r < 4; ++r) { redS[w][r] = s[r]; redSS[w][r] = ss[r]; }
    }
    __syncthreads();
#pragma unroll
    for (int r = 0; r < 4; ++r) {
        s[r]  = redS[0][r] + redS[1][r] + redS[2][r] + redS[3][r];
        ss[r] = redSS[0][r] + redSS[1][r] + redSS[2][r] + redSS[3][r];
    }
#pragma unroll
    for (int r = 0; r < 4; ++r) {
        const float mu  = s[r] * (1.0f / NN);
        const float var = ss[r] * (1.0f / NN) - mu * mu;
        const float inv = rsqrtf(var + 1e-5f);
        float4 o;
        o.x = fmaxf(0.f, (acc[r].x - mu) * inv);
        o.y = fmaxf(0.f, (acc[r].y - mu) * inv);
        o.z = fmaxf(0.f, (acc[r].z - mu) * inv);
        o.w = fmaxf(0.f, (acc[r].w - mu) * inv);
        const int bt = (r & 1) ? bt1 : bt0;
        float* dst = nullptr;
        if (r < 2) dst = ws + XN_OFF + (size_t)bt * NN;
        else if ((bt & 31) > 0) dst = ws + TN_OFF + (size_t)(bt - 1) * NN;
        if (dst) ((float4*)dst)[tid] = o;
    }
}

// ---------------- kernel 2: 4-role persistent pipeline ----------------
__device__ __forceinline__ float ald(const float* p) {
    return __hip_atomic_load(p, __ATOMIC_RELAXED, __HIP_MEMORY_SCOPE_AGENT);
}
__device__ __forceinline__ void ast(float* p, float v) {
    __hip_atomic_store(p, v, __ATOMIC_RELAXED, __HIP_MEMORY_SCOPE_AGENT);
}
__device__ __forceinline__ void poll_acq(const unsigned* c, unsigned target) {
    int g = 0;
    while (__hip_atomic_load(c, __ATOMIC_ACQUIRE, __HIP_MEMORY_SCOPE_AGENT) < target) {
        __builtin_amdgcn_s_sleep(1);
        if (++g > (1 << 22)) break;  // fail visibly, never hang
    }
}

__global__ __launch_bounds__(512, 2) void mega_kernel(
    const float* __restrict__ Dy, float* __restrict__ out, float* __restrict__ ws)
{
    __shared__ float sh[6144];   // stages 0-2: padded p-vector (1088); stage 3: r[1024][4] + partial[2048]
    const int blk = blockIdx.x;  // 0..223
    const int tid = threadIdx.x;

    float* pb      = ws + PB_OFF;
    float* rb      = ws + RB_OFF;
    unsigned* cnt  = (unsigned*)(ws + CNT_OFF);   // [(bt*2+ph)*32]
    unsigned* rcnt = (unsigned*)(ws + RCNT_OFF);  // [bt*32]

    if (blk < 192) {
        // ---- chain stages 0,1,2 ----
        const int stage = blk >> 6;
        const int b     = (blk >> 4) & 3;
        const int wg    = blk & 15;
        const int lane  = tid & 63;
        const int w     = tid >> 6;
        const int colbase = wg * 64 + w * 8;   // wave owns cols colbase..+7
        const int row0    = lane * 16;         // lane owns rows row0..+15
        const float* xn = ws + XN_OFF + (size_t)b * TT * NN;
        const float* tn = ws + TN_OFF + (size_t)b * TT * NN;

        float G[16][8];
#pragma unroll
        for (int i = 0; i < 16; ++i)
#pragma unroll
            for (int c = 0; c < 8; ++c)
                G[i][c] = (row0 + i == colbase + c) ? 0.01f : 0.0f;

#pragma unroll 1
        for (int t = 0; t < TT; ++t) {
            const int bt = b * TT + t;
            float* p1 = pb + (size_t)bt * 2 * NN;
            float* p2 = p1 + NN;

            float in[16], x[16];
            if (stage == 0) {
                const float4* xp = (const float4*)(xn + (size_t)t * NN + row0);
                float4 q0 = xp[0], q1 = xp[1], q2 = xp[2], q3 = xp[3];
                in[0]=q0.x; in[1]=q0.y; in[2]=q0.z; in[3]=q0.w;
                in[4]=q1.x; in[5]=q1.y; in[6]=q1.z; in[7]=q1.w;
                in[8]=q2.x; in[9]=q2.y; in[10]=q2.z; in[11]=q2.w;
                in[12]=q3.x; in[13]=q3.y; in[14]=q3.z; in[15]=q3.w;
#pragma unroll
                for (int j = 0; j < 16; ++j) x[j] = in[j];
            } else {
                const float* src = (stage == 1) ? p1 : p2;
                if (tid == 0) poll_acq(cnt + (size_t)(bt * 2 + (stage - 1)) * 32, 16u);
                __syncthreads();
                // exactly-once cooperative read -> padded LDS
                float a0 = ald(src + tid), a1 = ald(src + tid + 512);
                sh[tid + (tid >> 4)] = a0;
                sh[(tid + 512) + ((tid + 512) >> 4)] = a1;
                __syncthreads();
#pragma unroll
                for (int j = 0; j < 16; ++j) in[j] = sh[lane * 17 + j];
            }

            // matvec: acc[c] = partial sum for col colbase+c over this lane's rows
            float acc[8] = {0.f,0.f,0.f,0.f,0.f,0.f,0.f,0.f};
#pragma unroll
            for (int i = 0; i < 16; ++i)
#pragma unroll
                for (int c = 0; c < 8; ++c) acc[c] += in[i] * G[i][c];

            // reduce-scatter: lane ends with full sum for col colbase + (lane&7)
            float t4[8];
#pragma unroll
            for (int c = 0; c < 8; ++c) t4[c] = __shfl_xor(acc[c], 4, 64);
            const bool k2 = (lane & 4) != 0;
            float s4[4];
#pragma unroll
            for (int k = 0; k < 4; ++k) s4[k] = k2 ? (acc[4+k] + t4[4+k]) : (acc[k] + t4[k]);
            float t2[4];
#pragma unroll
            for (int k = 0; k < 4; ++k) t2[k] = __shfl_xor(s4[k], 2, 64);
            const bool k1 = (lane & 2) != 0;
            float s2[2];
#pragma unroll
            for (int k = 0; k < 2; ++k) s2[k] = k1 ? (s4[2+k] + t2[2+k]) : (s4[k] + t2[k]);
            float t1[2];
#pragma unroll
            for (int k = 0; k < 2; ++k) t1[k] = __shfl_xor(s2[k], 1, 64);
            float v = (lane & 1) ? (s2[1] + t1[1]) : (s2[0] + t1[0]);
            v += __shfl_xor(v, 8, 64);
            v += __shfl_xor(v, 16, 64);
            v += __shfl_xor(v, 32, 64);

            if (stage == 0) {
                if (lane < 8) ast(p1 + colbase + lane, v);
                __syncthreads();   // drains vmcnt for all waves' stores
                if (tid == 0)
                    __hip_atomic_fetch_add(cnt + (size_t)(bt * 2 + 0) * 32, 1u,
                                           __ATOMIC_RELEASE, __HIP_MEMORY_SCOPE_AGENT);
            } else if (stage == 1) {
                if (lane < 8) ast(p2 + colbase + lane, v);
                __syncthreads();
                if (tid == 0)
                    __hip_atomic_fetch_add(cnt + (size_t)(bt * 2 + 1) * 32, 1u,
                                           __ATOMIC_RELEASE, __HIP_MEMORY_SCOPE_AGENT);
            } else {
                float v1own = ald(p1 + colbase + (lane & 7));
                float v2own = ald(p2 + colbase + (lane & 7));
                float r = fmaxf(v, fmaxf(v1own, v2own));
                if (lane < 8) ast(rb + (size_t)bt * NN + colbase + lane, r);
                __syncthreads();
                if (tid == 0)
                    __hip_atomic_fetch_add(rcnt + (size_t)bt * 32, 1u,
                                           __ATOMIC_RELEASE, __HIP_MEMORY_SCOPE_AGENT);
            }

            // G update: G = max(G, 0.5*xn_t*tn_t^T), skip last step
            if (t < TT - 1) {
                if (stage != 0) {
                    const float4* xp = (const float4*)(xn + (size_t)t * NN + row0);
                    float4 q0 = xp[0], q1 = xp[1], q2 = xp[2], q3 = xp[3];
                    x[0]=q0.x; x[1]=q0.y; x[2]=q0.z; x[3]=q0.w;
                    x[4]=q1.x; x[5]=q1.y; x[6]=q1.z; x[7]=q1.w;
                    x[8]=q2.x; x[9]=q2.y; x[10]=q2.z; x[11]=q2.w;
                    x[12]=q3.x; x[13]=q3.y; x[14]=q3.z; x[15]=q3.w;
                }
                const float4 ta = *(const float4*)(tn + (size_t)t * NN + colbase);
                const float4 tb = *(const float4*)(tn + (size_t)t * NN + colbase + 4);
                const float tv[8] = {0.5f*ta.x, 0.5f*ta.y, 0.5f*ta.z, 0.5f*ta.w,
                                     0.5f*tb.x, 0.5f*tb.y, 0.5f*tb.z, 0.5f*tb.w};
#pragma unroll
                for (int c = 0; c < 8; ++c)
#pragma unroll
                    for (int i = 0; i < 16; ++i)
                        G[i][c] = fmaxf(G[i][c], x[i] * tv[c]);
            }
        }
    } else {
        // ---- stage 3: y = relu(r @ Dy) for 4 consecutive steps, single Dy pass ----
        const int k   = blk - 192;        // 0..31
        const int b   = k >> 3;
        const int t0  = (k & 7) * 4;
        const int bt0 = b * TT + t0;
        // rcnt is monotone in t within a batch (same 16 WGs proceed sequentially)
        if (tid == 0) poll_acq(rcnt + (size_t)(bt0 + 3) * 32, 16u);
        __syncthreads();
#pragma unroll
        for (int j = 0; j < 4; ++j) {
            const float* r = rb + (size_t)(bt0 + j) * NN;
            sh[tid * 4 + j]         = ald(r + tid);
            sh[(tid + 512) * 4 + j] = ald(r + tid + 512);
        }
        __syncthreads();
        const int d = tid & 255, h = tid >> 8;
        float acc[4] = {0.f, 0.f, 0.f, 0.f};
        const int n0 = h * 512;
#pragma unroll 8
        for (int n = n0; n < n0 + 512; ++n) {
            const float dv = Dy[(size_t)n * DD + d];
            const float4 rv = *(const float4*)&sh[n * 4];   // wave-uniform n -> LDS broadcast
            acc[0] += rv.x * dv; acc[1] += rv.y * dv;
            acc[2] += rv.z * dv; acc[3] += rv.w * dv;
        }
#pragma unroll
        for (int j = 0; j < 4; ++j) sh[4096 + (h * 4 + j) * 256 + d] = acc[j];
        __syncthreads();
        if (tid < 256) {
#pragma unroll
            for (int j = 0; j < 4; ++j)
                out[(size_t)(bt0 + j) * DD + tid] =
                    fmaxf(0.f, sh[4096 + j * 256 + tid] + sh[4096 + (4 + j) * 256 + tid]);
        }
    }
}

extern "C" void kernel_launch(void* const* d_in, const int* in_sizes, int n_in,
                              void* d_out, int out_size, void* d_ws, size_t ws_size,
                              hipStream_t stream) {
    const float* x_seq   = (const float*)d_in[0];
    const float* targets = (const float*)d_in[1];
    const float* E       = (const float*)d_in[2];
    const float* Dy      = (const float*)d_in[3];
    float* out = (float*)d_out;
    float* ws  = (float*)d_ws;

    // zero only the padded counters (data is flag-protected)
    hipMemsetAsync(ws + CNT_OFF, 0, (size_t)(WS_END - CNT_OFF) * sizeof(float), stream);

    precompute_kernel<<<BB * TT / 2, 256, 0, stream>>>(x_seq, targets, E, ws);
    mega_kernel<<<224, 512, 0, stream>>>(Dy, out, ws);
}